// Round 3
// baseline (521.916 us; speedup 1.0000x reference)
//
#include <hip/hip_runtime.h>
#include <hip/hip_bf16.h>
#include <stdint.h>

// Problem dims (fixed by the reference setup_inputs):
//   a_previous [8192, 4096] f32, theta [4096, 4098] f32, aging [4096, 4098] f32
//   out [8192, 4096] f32
#define M_DIM 8192
#define N_DIM 4096
#define K_IN  4096          // n_in
#define NC    (K_IN + 2)    // 4098 theta/aging columns
#define K_DIM (2 * K_IN)    // GEMM K: [a | inv(a)] concatenated

#define BM 256
#define BN 256
#define BK 64
#define NT (K_DIM / BK)     // 128 K-tiles

typedef __attribute__((ext_vector_type(8))) short short8_t;   // 8 bf16 (4 VGPRs)
typedef __attribute__((ext_vector_type(4))) float f32x4;      // MFMA acc

__device__ __forceinline__ unsigned short f2bf(float f) {
  union { float f; unsigned u; } v; v.f = f;
  unsigned u = v.u;
  return (unsigned short)((u + 0x7FFFu + ((u >> 16) & 1u)) >> 16);
}

__device__ __forceinline__ float fast_tanh(float y) {
  float e = __expf(2.0f * y);
  return 1.0f - 2.0f * __builtin_amdgcn_rcpf(1.0f + e);
}

// ---------------------------------------------------------------------------
// prep_A: A' = [bf16(a) | bf16(inv(a))], shape [8192][8192] bf16
// ---------------------------------------------------------------------------
__global__ __launch_bounds__(256) void prep_A(const float* __restrict__ a,
                                              unsigned short* __restrict__ Ap) {
  int idx = blockIdx.x * 256 + threadIdx.x;
  int j  = idx >> 10;
  int k4 = (idx & 1023) << 2;
  float4 v = reinterpret_cast<const float4*>(a)[idx];
  float xs[4] = {v.x, v.y, v.z, v.w};
  ushort4 lv, rv;
  unsigned short l[4], r[4];
#pragma unroll
  for (int t = 0; t < 4; ++t) {
    float x = xs[t];
    l[t] = f2bf(x);
    float tnh = fast_tanh((x + 0.056f) * 3.858f);
    r[t] = f2bf(0.104f - 0.899f * tnh);
  }
  lv.x = l[0]; lv.y = l[1]; lv.z = l[2]; lv.w = l[3];
  rv.x = r[0]; rv.y = r[1]; rv.z = r[2]; rv.w = r[3];
  size_t base = (size_t)j * K_DIM + k4;
  *reinterpret_cast<ushort4*>(Ap + base)        = lv;
  *reinterpret_cast<ushort4*>(Ap + base + K_IN) = rv;
}

// ---------------------------------------------------------------------------
// prep_B: th = st(theta*aging); W = |th|/rowsum; B' = [Wp | Wn] bf16; corr f32
// ---------------------------------------------------------------------------
__global__ __launch_bounds__(256) void prep_B(const float* __restrict__ theta,
                                              const float* __restrict__ aging,
                                              unsigned short* __restrict__ Bp,
                                              float* __restrict__ corr) {
  __shared__ float th_s[NC];
  __shared__ float red[256];
  int i = blockIdx.x;
  int tid = threadIdx.x;
  const float* tr = theta + (size_t)i * NC;
  const float* ar = aging + (size_t)i * NC;
  float psum = 0.f;
  for (int k = tid; k < NC; k += 256) {
    float th = tr[k] * ar[k];
    if (fabsf(th) < 0.01f) th = 0.f;
    th_s[k] = th;
    psum += fabsf(th);
  }
  red[tid] = psum;
  __syncthreads();
  for (int s = 128; s > 0; s >>= 1) {
    if (tid < s) red[tid] += red[tid + s];
    __syncthreads();
  }
  float inv_sum = 1.0f / red[0];
  unsigned short* out = Bp + (size_t)i * K_DIM;
  for (int k = tid; k < K_IN; k += 256) {
    float th = th_s[k];
    float w = fabsf(th) * inv_sum;
    out[k]        = f2bf((th >= 0.f) ? w : 0.f);
    out[K_IN + k] = f2bf((th <  0.f) ? w : 0.f);
  }
  if (tid == 0) {
    float th1 = th_s[K_IN];
    float th2 = th_s[K_IN + 1];
    float w1 = fabsf(th1) * inv_sum;
    float w2 = fabsf(th2) * inv_sum;
    float inv1 = 0.104f - 0.899f * fast_tanh((1.0f + 0.056f) * 3.858f);
    float inv0 = 0.104f - 0.899f * fast_tanh((0.0f + 0.056f) * 3.858f);
    float c = (th1 >= 0.f) ? w1 : w1 * inv1;
    c += (th2 >= 0.f) ? 0.0f : w2 * inv0;
    corr[i] = c;
  }
}

// ---------------------------------------------------------------------------
// gemm_fused: 256x256 tile, BK=64, 8 waves (2Mx4N), 4-phase/K-tile schedule.
// R3 change vs R2: uniform deep prefetch — ALL of tile W+2 staged at window W
// (B halves at p2, A halves at p3), vmcnt(8) once per K-tile (full next tile
// in flight across the boundary). Leads: B 6 phases, A 5 phases.
// Region ledger:
//   B region of buf (W&1): last ds_read at W p1 -> glds B(W+2) issued p2 (after
//     p1's trailing barrier). A region: last ds_read at W p2 -> glds A(W+2) at
//     p3. Read side: tile T first read at T p0, covered by T-1 p3's vmcnt(8)
//     (the 8 loads newer than tile T's stages are exactly B(T+1)+A(T+1)).
// ---------------------------------------------------------------------------
__global__ __launch_bounds__(512, 2) void gemm_fused(const unsigned short* __restrict__ A,
                                                     const unsigned short* __restrict__ B,
                                                     const float* __restrict__ corr,
                                                     float* __restrict__ C) {
  extern __shared__ unsigned short lds[];   // 65536 elems = 128 KiB
  const int tid  = threadIdx.x;
  const int lane = tid & 63;
  const int wid  = tid >> 6;     // 0..7
  const int wr   = wid >> 2;     // 0..1  -> M offset wr*128
  const int wc   = wid & 3;      // 0..3  -> N offset wc*64
  const int fr   = lane & 15;
  const int fk8  = (lane >> 4) * 8;

  // T1: XCD-aware swizzle; nwg = 512, divisible by 8 -> bijective
  const int bid = (int)blockIdx.x;
  const int sw  = (bid & 7) * 64 + (bid >> 3);
  const int bm0 = (sw >> 4) * BM;     // 32 M-blocks
  const int bn0 = (sw & 15) * BN;     // 16 N-blocks

  // staging: linear LDS dest (glds), per-lane GLOBAL source col pre-swizzled
  const int colsw = ((tid & 7) * 8) ^ (((tid >> 3) & 7) << 3);
  const unsigned short* gA = A + (size_t)(bm0 + (tid >> 3)) * K_DIM + colsw;
  const unsigned short* gB = B + (size_t)(bn0 + (tid >> 3)) * K_DIM + colsw;
  char* ldsb = (char*)lds;
  const int dst_t = tid * 16;

  // read-side swizzled fragment offsets
  const int flip = (fr & 7) << 3;
  const int cs0  = fk8 ^ flip;
  const int cs1  = (32 + fk8) ^ flip;
  const int aRow = (wr * 128 + fr) * 64;
  const int bRow = (wc * 64 + fr) * 64;

  f32x4 acc[8][4] = {};

#define STAGE(ISA, H, T) do {                                                        \
    const unsigned short* _g = (ISA) ? gA : gB;                                      \
    const size_t _go = (size_t)((H) * 128) * K_DIM + (size_t)(T) * BK;               \
    char* _l = ldsb + (((T) & 1) * 65536) + ((ISA) ? 0 : 32768) + (H) * 16384 + dst_t; \
    __builtin_amdgcn_global_load_lds(                                                \
        (const __attribute__((address_space(1))) unsigned int*)(_g + _go),           \
        (__attribute__((address_space(3))) unsigned int*)_l, 16, 0, 0);              \
    __builtin_amdgcn_global_load_lds(                                                \
        (const __attribute__((address_space(1))) unsigned int*)(_g + _go + (size_t)64 * K_DIM), \
        (__attribute__((address_space(3))) unsigned int*)(_l + 8192), 16, 0, 0);     \
  } while (0)

#define MFMA(a, b, c) __builtin_amdgcn_mfma_f32_16x16x32_bf16((a), (b), (c), 0, 0, 0)

  // ---- prologue: tile0 + tile1 fully staged (16 loads); wait tile0 (8 left)
  STAGE(0, 0, 0); STAGE(0, 1, 0); STAGE(1, 0, 0); STAGE(1, 1, 0);
  STAGE(0, 0, 1); STAGE(0, 1, 1); STAGE(1, 0, 1); STAGE(1, 1, 1);
  asm volatile("s_waitcnt vmcnt(8)" ::: "memory");
  __builtin_amdgcn_s_barrier();
  asm volatile("" ::: "memory");

#pragma unroll 2
  for (int W = 0; W < NT; ++W) {
    const unsigned short* pa = lds + (W & 1) * 32768 + aRow;
    const unsigned short* pb = lds + (W & 1) * 32768 + 16384 + bRow;
    short8_t af[4][2], bf[4][2];

    // ===== phase 0: read A m0-3 (8) + B n0-1 (4); MFMA [m0-3]x[n0-1]
#pragma unroll
    for (int m = 0; m < 4; ++m) {
      af[m][0] = *(const short8_t*)(pa + m * 1024 + cs0);
      af[m][1] = *(const short8_t*)(pa + m * 1024 + cs1);
    }
#pragma unroll
    for (int n = 0; n < 2; ++n) {
      bf[n][0] = *(const short8_t*)(pb + n * 1024 + cs0);
      bf[n][1] = *(const short8_t*)(pb + n * 1024 + cs1);
    }
    asm volatile("s_waitcnt lgkmcnt(8)" ::: "memory");   // early-drain hint (12 reads)
    __builtin_amdgcn_s_barrier();
    asm volatile("s_waitcnt lgkmcnt(0)" ::: "memory");
    __builtin_amdgcn_sched_barrier(0);
    __builtin_amdgcn_s_setprio(1);
#pragma unroll
    for (int m = 0; m < 4; ++m)
#pragma unroll
      for (int n = 0; n < 2; ++n) {
        acc[m][n] = MFMA(af[m][0], bf[n][0], acc[m][n]);
        acc[m][n] = MFMA(af[m][1], bf[n][1], acc[m][n]);
      }
    __builtin_amdgcn_s_setprio(0);
    __builtin_amdgcn_s_barrier();
    asm volatile("" ::: "memory");

    // ===== phase 1: read B n2-3 (4); MFMA [m0-3]x[n2-3]
#pragma unroll
    for (int n = 2; n < 4; ++n) {
      bf[n][0] = *(const short8_t*)(pb + n * 1024 + cs0);
      bf[n][1] = *(const short8_t*)(pb + n * 1024 + cs1);
    }
    __builtin_amdgcn_s_barrier();
    asm volatile("s_waitcnt lgkmcnt(0)" ::: "memory");
    __builtin_amdgcn_sched_barrier(0);
    __builtin_amdgcn_s_setprio(1);
#pragma unroll
    for (int m = 0; m < 4; ++m)
#pragma unroll
      for (int n = 2; n < 4; ++n) {
        acc[m][n] = MFMA(af[m][0], bf[n][0], acc[m][n]);
        acc[m][n] = MFMA(af[m][1], bf[n][1], acc[m][n]);
      }
    __builtin_amdgcn_s_setprio(0);
    __builtin_amdgcn_s_barrier();
    asm volatile("" ::: "memory");

    // ===== phase 2: read A m4-7 (8); stage B0,B1(W+2); MFMA [m4-7]x[n0-1]
#pragma unroll
    for (int m = 0; m < 4; ++m) {
      af[m][0] = *(const short8_t*)(pa + (m + 4) * 1024 + cs0);
      af[m][1] = *(const short8_t*)(pa + (m + 4) * 1024 + cs1);
    }
    if (W + 2 < NT) { STAGE(0, 0, W + 2); STAGE(0, 1, W + 2); }
    __builtin_amdgcn_s_barrier();
    asm volatile("s_waitcnt lgkmcnt(0)" ::: "memory");
    __builtin_amdgcn_sched_barrier(0);
    __builtin_amdgcn_s_setprio(1);
#pragma unroll
    for (int m = 0; m < 4; ++m)
#pragma unroll
      for (int n = 0; n < 2; ++n) {
        acc[m + 4][n] = MFMA(af[m][0], bf[n][0], acc[m + 4][n]);
        acc[m + 4][n] = MFMA(af[m][1], bf[n][1], acc[m + 4][n]);
      }
    __builtin_amdgcn_s_setprio(0);
    __builtin_amdgcn_s_barrier();
    asm volatile("" ::: "memory");

    // ===== phase 3: stage A0,A1(W+2); MFMA [m4-7]x[n2-3]; counted vmcnt
    if (W + 2 < NT) { STAGE(1, 0, W + 2); STAGE(1, 1, W + 2); }
    __builtin_amdgcn_s_barrier();
    __builtin_amdgcn_sched_barrier(0);
    __builtin_amdgcn_s_setprio(1);
#pragma unroll
    for (int m = 0; m < 4; ++m)
#pragma unroll
      for (int n = 2; n < 4; ++n) {
        acc[m + 4][n] = MFMA(af[m][0], bf[n][0], acc[m + 4][n]);
        acc[m + 4][n] = MFMA(af[m][1], bf[n][1], acc[m + 4][n]);
      }
    __builtin_amdgcn_s_setprio(0);
    if (W < NT - 2) { asm volatile("s_waitcnt vmcnt(8)" ::: "memory"); }
    else            { asm volatile("s_waitcnt vmcnt(0)" ::: "memory"); }
    __builtin_amdgcn_s_barrier();
    asm volatile("" ::: "memory");
  }

  // ---- epilogue: z + corr, activation, store
  const int rb = (lane >> 4) * 4;
#pragma unroll
  for (int n = 0; n < 4; ++n) {
    const int col = bn0 + wc * 64 + n * 16 + fr;
    const float cr = corr[col];
#pragma unroll
    for (int mi = 0; mi < 8; ++mi) {
      const int row0 = bm0 + wr * 128 + mi * 16 + rb;
#pragma unroll
      for (int j = 0; j < 4; ++j) {
        float z = acc[mi][n][j] + cr;
        float e = __expf((z - 0.183f) * 48.2f);
        C[(size_t)(row0 + j) * N_DIM + col] = 1.096f - 1.924f * __builtin_amdgcn_rcpf(1.0f + e);
      }
    }
  }
#undef STAGE
#undef MFMA
}

// ---------------------------------------------------------------------------
extern "C" void kernel_launch(void* const* d_in, const int* in_sizes, int n_in,
                              void* d_out, int out_size, void* d_ws, size_t ws_size,
                              hipStream_t stream) {
  (void)in_sizes; (void)n_in; (void)out_size; (void)ws_size;
  const float* a_prev = (const float*)d_in[0];
  const float* theta  = (const float*)d_in[1];
  const float* aging  = (const float*)d_in[2];
  float* out = (float*)d_out;

  char* ws = (char*)d_ws;
  unsigned short* Ap = (unsigned short*)ws;                                  // 134.2 MB
  unsigned short* Bp = (unsigned short*)(ws + (size_t)M_DIM * K_DIM * 2);    //  67.1 MB
  float* corr = (float*)(ws + (size_t)M_DIM * K_DIM * 2 + (size_t)N_DIM * K_DIM * 2);

  prep_A<<<(M_DIM * K_IN / 4) / 256, 256, 0, stream>>>(a_prev, Ap);
  prep_B<<<N_DIM, 256, 0, stream>>>(theta, aging, Bp, corr);

  (void)hipFuncSetAttribute((const void*)gemm_fused,
                            hipFuncAttributeMaxDynamicSharedMemorySize, 131072);
  gemm_fused<<<dim3((M_DIM / BM) * (N_DIM / BN)), dim3(512), 131072, stream>>>(Ap, Bp, corr, out);
}

// Round 4
// 458.701 us; speedup vs baseline: 1.1378x; 1.1378x over previous
//
#include <hip/hip_runtime.h>
#include <hip/hip_bf16.h>
#include <stdint.h>

// Problem dims (fixed by the reference setup_inputs):
//   a_previous [8192, 4096] f32, theta [4096, 4098] f32, aging [4096, 4098] f32
//   out [8192, 4096] f32
#define M_DIM 8192
#define N_DIM 4096
#define K_IN  4096          // n_in
#define NC    (K_IN + 2)    // 4098 theta/aging columns
#define K_DIM (2 * K_IN)    // GEMM K: [a | inv(a)] concatenated

#define BM 256
#define BN 256
#define BK 64
#define NT (K_DIM / BK)     // 128 K-tiles

typedef __attribute__((ext_vector_type(8))) short short8_t;   // 8 bf16 (4 VGPRs)
typedef __attribute__((ext_vector_type(4))) float f32x4;      // MFMA acc

__device__ __forceinline__ unsigned short f2bf(float f) {
  union { float f; unsigned u; } v; v.f = f;
  unsigned u = v.u;
  return (unsigned short)((u + 0x7FFFu + ((u >> 16) & 1u)) >> 16);
}

__device__ __forceinline__ float fast_tanh(float y) {
  float e = __expf(2.0f * y);
  return 1.0f - 2.0f * __builtin_amdgcn_rcpf(1.0f + e);
}

// ---------------------------------------------------------------------------
// prep_A: A' = [bf16(a) | bf16(inv(a))], shape [8192][8192] bf16
// ---------------------------------------------------------------------------
__global__ __launch_bounds__(256) void prep_A(const float* __restrict__ a,
                                              unsigned short* __restrict__ Ap) {
  int idx = blockIdx.x * 256 + threadIdx.x;
  int j  = idx >> 10;
  int k4 = (idx & 1023) << 2;
  float4 v = reinterpret_cast<const float4*>(a)[idx];
  float xs[4] = {v.x, v.y, v.z, v.w};
  ushort4 lv, rv;
  unsigned short l[4], r[4];
#pragma unroll
  for (int t = 0; t < 4; ++t) {
    float x = xs[t];
    l[t] = f2bf(x);
    float tnh = fast_tanh((x + 0.056f) * 3.858f);
    r[t] = f2bf(0.104f - 0.899f * tnh);
  }
  lv.x = l[0]; lv.y = l[1]; lv.z = l[2]; lv.w = l[3];
  rv.x = r[0]; rv.y = r[1]; rv.z = r[2]; rv.w = r[3];
  size_t base = (size_t)j * K_DIM + k4;
  *reinterpret_cast<ushort4*>(Ap + base)        = lv;
  *reinterpret_cast<ushort4*>(Ap + base + K_IN) = rv;
}

// ---------------------------------------------------------------------------
// prep_B: th = st(theta*aging); W = |th|/rowsum; B' = [Wp | Wn] bf16; corr f32
// ---------------------------------------------------------------------------
__global__ __launch_bounds__(256) void prep_B(const float* __restrict__ theta,
                                              const float* __restrict__ aging,
                                              unsigned short* __restrict__ Bp,
                                              float* __restrict__ corr) {
  __shared__ float th_s[NC];
  __shared__ float red[256];
  int i = blockIdx.x;
  int tid = threadIdx.x;
  const float* tr = theta + (size_t)i * NC;
  const float* ar = aging + (size_t)i * NC;
  float psum = 0.f;
  for (int k = tid; k < NC; k += 256) {
    float th = tr[k] * ar[k];
    if (fabsf(th) < 0.01f) th = 0.f;
    th_s[k] = th;
    psum += fabsf(th);
  }
  red[tid] = psum;
  __syncthreads();
  for (int s = 128; s > 0; s >>= 1) {
    if (tid < s) red[tid] += red[tid + s];
    __syncthreads();
  }
  float inv_sum = 1.0f / red[0];
  unsigned short* out = Bp + (size_t)i * K_DIM;
  for (int k = tid; k < K_IN; k += 256) {
    float th = th_s[k];
    float w = fabsf(th) * inv_sum;
    out[k]        = f2bf((th >= 0.f) ? w : 0.f);
    out[K_IN + k] = f2bf((th <  0.f) ? w : 0.f);
  }
  if (tid == 0) {
    float th1 = th_s[K_IN];
    float th2 = th_s[K_IN + 1];
    float w1 = fabsf(th1) * inv_sum;
    float w2 = fabsf(th2) * inv_sum;
    float inv1 = 0.104f - 0.899f * fast_tanh((1.0f + 0.056f) * 3.858f);
    float inv0 = 0.104f - 0.899f * fast_tanh((0.0f + 0.056f) * 3.858f);
    float c = (th1 >= 0.f) ? w1 : w1 * inv1;
    c += (th2 >= 0.f) ? 0.0f : w2 * inv0;
    corr[i] = c;
  }
}

// ---------------------------------------------------------------------------
// gemm_fused: 256x256 tile, BK=64, 8 waves (2Mx4N), 4-phase/K-tile schedule
// with ONE barrier per phase (m201-faithful): {ds_reads ∥ stage -> barrier ->
// lgkmcnt(0) -> setprio(1) MFMA x16 setprio(0)}. A wave issues phase p+1's
// ds_reads right after its MFMA(p) issues -> LDS reads hide under the matrix
// pipe drain. vmcnt(8) once per K-tile at p3 (tile W+1 forced complete before
// its p0 reads; tile W+2's 8 loads stay in flight across the boundary).
// Region ledger (buf = W&1): B region last read-issue at p1, staged p2
// (p1-barrier + MFMA cluster between). A region last read-issue at p2, staged
// p3. Tile T's reads at T p0 follow T-1 p3's vmcnt(8)+barrier. Tail: W>=NT-2
// uses vmcnt(0) (no new stages issued; vmcnt(8) would not force W+1).
// ---------------------------------------------------------------------------
__global__ __launch_bounds__(512, 2) void gemm_fused(const unsigned short* __restrict__ A,
                                                     const unsigned short* __restrict__ B,
                                                     const float* __restrict__ corr,
                                                     float* __restrict__ C) {
  extern __shared__ unsigned short lds[];   // 65536 elems = 128 KiB
  const int tid  = threadIdx.x;
  const int lane = tid & 63;
  const int wid  = tid >> 6;     // 0..7
  const int wr   = wid >> 2;     // 0..1  -> M offset wr*128
  const int wc   = wid & 3;      // 0..3  -> N offset wc*64
  const int fr   = lane & 15;
  const int fk8  = (lane >> 4) * 8;

  // T1: XCD-aware swizzle; nwg = 512, divisible by 8 -> bijective
  const int bid = (int)blockIdx.x;
  const int sw  = (bid & 7) * 64 + (bid >> 3);
  const int bm0 = (sw >> 4) * BM;     // 32 M-blocks
  const int bn0 = (sw & 15) * BN;     // 16 N-blocks

  // staging: linear LDS dest (glds), per-lane GLOBAL source col pre-swizzled
  const int colsw = ((tid & 7) * 8) ^ (((tid >> 3) & 7) << 3);
  const unsigned short* gA = A + (size_t)(bm0 + (tid >> 3)) * K_DIM + colsw;
  const unsigned short* gB = B + (size_t)(bn0 + (tid >> 3)) * K_DIM + colsw;
  char* ldsb = (char*)lds;
  const int dst_t = tid * 16;

  // read-side swizzled fragment offsets
  const int flip = (fr & 7) << 3;
  const int cs0  = fk8 ^ flip;
  const int cs1  = (32 + fk8) ^ flip;
  const int aRow = (wr * 128 + fr) * 64;
  const int bRow = (wc * 64 + fr) * 64;

  f32x4 acc[8][4] = {};

#define STAGE(ISA, H, T) do {                                                        \
    const unsigned short* _g = (ISA) ? gA : gB;                                      \
    const size_t _go = (size_t)((H) * 128) * K_DIM + (size_t)(T) * BK;               \
    char* _l = ldsb + (((T) & 1) * 65536) + ((ISA) ? 0 : 32768) + (H) * 16384 + dst_t; \
    __builtin_amdgcn_global_load_lds(                                                \
        (const __attribute__((address_space(1))) unsigned int*)(_g + _go),           \
        (__attribute__((address_space(3))) unsigned int*)_l, 16, 0, 0);              \
    __builtin_amdgcn_global_load_lds(                                                \
        (const __attribute__((address_space(1))) unsigned int*)(_g + _go + (size_t)64 * K_DIM), \
        (__attribute__((address_space(3))) unsigned int*)(_l + 8192), 16, 0, 0);     \
  } while (0)

#define MFMA(a, b, c) __builtin_amdgcn_mfma_f32_16x16x32_bf16((a), (b), (c), 0, 0, 0)

  // ---- prologue: tile0 + tile1 fully staged (16 loads); wait tile0 (8 left)
  STAGE(0, 0, 0); STAGE(0, 1, 0); STAGE(1, 0, 0); STAGE(1, 1, 0);
  STAGE(0, 0, 1); STAGE(0, 1, 1); STAGE(1, 0, 1); STAGE(1, 1, 1);
  asm volatile("s_waitcnt vmcnt(8)" ::: "memory");
  __builtin_amdgcn_s_barrier();

#pragma unroll 2
  for (int W = 0; W < NT; ++W) {
    const unsigned short* pa = lds + (W & 1) * 32768 + aRow;
    const unsigned short* pb = lds + (W & 1) * 32768 + 16384 + bRow;
    short8_t af[4][2], bf[4][2];

    // ===== phase 0: read A m0-3 (8) + B n0-1 (4) | barrier | MFMA q00
#pragma unroll
    for (int m = 0; m < 4; ++m) {
      af[m][0] = *(const short8_t*)(pa + m * 1024 + cs0);
      af[m][1] = *(const short8_t*)(pa + m * 1024 + cs1);
    }
#pragma unroll
    for (int n = 0; n < 2; ++n) {
      bf[n][0] = *(const short8_t*)(pb + n * 1024 + cs0);
      bf[n][1] = *(const short8_t*)(pb + n * 1024 + cs1);
    }
    __builtin_amdgcn_s_barrier();
    asm volatile("s_waitcnt lgkmcnt(0)" ::: "memory");
    __builtin_amdgcn_sched_barrier(0);
    __builtin_amdgcn_s_setprio(1);
#pragma unroll
    for (int m = 0; m < 4; ++m)
#pragma unroll
      for (int n = 0; n < 2; ++n) {
        acc[m][n] = MFMA(af[m][0], bf[n][0], acc[m][n]);
        acc[m][n] = MFMA(af[m][1], bf[n][1], acc[m][n]);
      }
    __builtin_amdgcn_s_setprio(0);

    // ===== phase 1: read B n2-3 (4) | barrier | MFMA q01
#pragma unroll
    for (int n = 2; n < 4; ++n) {
      bf[n][0] = *(const short8_t*)(pb + n * 1024 + cs0);
      bf[n][1] = *(const short8_t*)(pb + n * 1024 + cs1);
    }
    __builtin_amdgcn_s_barrier();
    asm volatile("s_waitcnt lgkmcnt(0)" ::: "memory");
    __builtin_amdgcn_sched_barrier(0);
    __builtin_amdgcn_s_setprio(1);
#pragma unroll
    for (int m = 0; m < 4; ++m)
#pragma unroll
      for (int n = 2; n < 4; ++n) {
        acc[m][n] = MFMA(af[m][0], bf[n][0], acc[m][n]);
        acc[m][n] = MFMA(af[m][1], bf[n][1], acc[m][n]);
      }
    __builtin_amdgcn_s_setprio(0);

    // ===== phase 2: read A m4-7 (8); stage B(W+2) | barrier | MFMA q10
#pragma unroll
    for (int m = 0; m < 4; ++m) {
      af[m][0] = *(const short8_t*)(pa + (m + 4) * 1024 + cs0);
      af[m][1] = *(const short8_t*)(pa + (m + 4) * 1024 + cs1);
    }
    if (W + 2 < NT) { STAGE(0, 0, W + 2); STAGE(0, 1, W + 2); }
    __builtin_amdgcn_s_barrier();
    asm volatile("s_waitcnt lgkmcnt(0)" ::: "memory");
    __builtin_amdgcn_sched_barrier(0);
    __builtin_amdgcn_s_setprio(1);
#pragma unroll
    for (int m = 0; m < 4; ++m)
#pragma unroll
      for (int n = 0; n < 2; ++n) {
        acc[m + 4][n] = MFMA(af[m][0], bf[n][0], acc[m + 4][n]);
        acc[m + 4][n] = MFMA(af[m][1], bf[n][1], acc[m + 4][n]);
      }
    __builtin_amdgcn_s_setprio(0);

    // ===== phase 3: stage A(W+2); counted vmcnt | barrier | MFMA q11
    if (W + 2 < NT) { STAGE(1, 0, W + 2); STAGE(1, 1, W + 2); }
    if (W < NT - 2) { asm volatile("s_waitcnt vmcnt(8)" ::: "memory"); }
    else            { asm volatile("s_waitcnt vmcnt(0)" ::: "memory"); }
    __builtin_amdgcn_s_barrier();
    __builtin_amdgcn_sched_barrier(0);
    __builtin_amdgcn_s_setprio(1);
#pragma unroll
    for (int m = 0; m < 4; ++m)
#pragma unroll
      for (int n = 2; n < 4; ++n) {
        acc[m + 4][n] = MFMA(af[m][0], bf[n][0], acc[m + 4][n]);
        acc[m + 4][n] = MFMA(af[m][1], bf[n][1], acc[m + 4][n]);
      }
    __builtin_amdgcn_s_setprio(0);
  }

  // ---- epilogue: z + corr, activation, store
  const int rb = (lane >> 4) * 4;
#pragma unroll
  for (int n = 0; n < 4; ++n) {
    const int col = bn0 + wc * 64 + n * 16 + fr;
    const float cr = corr[col];
#pragma unroll
    for (int mi = 0; mi < 8; ++mi) {
      const int row0 = bm0 + wr * 128 + mi * 16 + rb;
#pragma unroll
      for (int j = 0; j < 4; ++j) {
        float z = acc[mi][n][j] + cr;
        float e = __expf((z - 0.183f) * 48.2f);
        C[(size_t)(row0 + j) * N_DIM + col] = 1.096f - 1.924f * __builtin_amdgcn_rcpf(1.0f + e);
      }
    }
  }
#undef STAGE
#undef MFMA
}

// ---------------------------------------------------------------------------
extern "C" void kernel_launch(void* const* d_in, const int* in_sizes, int n_in,
                              void* d_out, int out_size, void* d_ws, size_t ws_size,
                              hipStream_t stream) {
  (void)in_sizes; (void)n_in; (void)out_size; (void)ws_size;
  const float* a_prev = (const float*)d_in[0];
  const float* theta  = (const float*)d_in[1];
  const float* aging  = (const float*)d_in[2];
  float* out = (float*)d_out;

  char* ws = (char*)d_ws;
  unsigned short* Ap = (unsigned short*)ws;                                  // 134.2 MB
  unsigned short* Bp = (unsigned short*)(ws + (size_t)M_DIM * K_DIM * 2);    //  67.1 MB
  float* corr = (float*)(ws + (size_t)M_DIM * K_DIM * 2 + (size_t)N_DIM * K_DIM * 2);

  prep_A<<<(M_DIM * K_IN / 4) / 256, 256, 0, stream>>>(a_prev, Ap);
  prep_B<<<N_DIM, 256, 0, stream>>>(theta, aging, Bp, corr);

  (void)hipFuncSetAttribute((const void*)gemm_fused,
                            hipFuncAttributeMaxDynamicSharedMemorySize, 131072);
  gemm_fused<<<dim3((M_DIM / BM) * (N_DIM / BN)), dim3(512), 131072, stream>>>(Ap, Bp, corr, out);
}

// Round 5
// 281.642 us; speedup vs baseline: 1.8531x; 1.6287x over previous
//
#include <hip/hip_runtime.h>
#include <hip/hip_bf16.h>
#include <stdint.h>

// Problem dims (fixed by the reference setup_inputs):
//   a_previous [8192, 4096] f32, theta [4096, 4098] f32, aging [4096, 4098] f32
//   out [8192, 4096] f32
#define M_DIM 8192
#define N_DIM 4096
#define K_IN  4096          // n_in
#define NC    (K_IN + 2)    // 4098 theta/aging columns
#define K_DIM (2 * K_IN)    // GEMM K: [a | inv(a)] concatenated, i8 elems (= bytes)

#define BM 256
#define BN 256
#define BKB 128             // K-bytes per tile (i8) -> 128 B rows, same as bf16 R4
#define NT (K_DIM / BKB)    // 64 K-tiles

typedef __attribute__((ext_vector_type(4))) int i32x4;   // i8 MFMA A/B frag + acc

__device__ __forceinline__ float fast_tanh(float y) {
  float e = __expf(2.0f * y);
  return 1.0f - 2.0f * __builtin_amdgcn_rcpf(1.0f + e);
}

__device__ __forceinline__ int q8(float x) {   // round-to-nearest, fits i8 by range
  return (int)__builtin_rintf(x);
}

// ---------------------------------------------------------------------------
// prep_A: A' = [i8(a*127) | i8(inv(a)*127)], shape [8192][8192] i8
// a in [0,1], inv(a) in (-0.80,-0.08) -> both fit scale 127 exactly
// ---------------------------------------------------------------------------
__global__ __launch_bounds__(256) void prep_A(const float* __restrict__ a,
                                              int8_t* __restrict__ Ap) {
  int idx = blockIdx.x * 256 + threadIdx.x;       // one float4 per thread
  int j  = idx >> 10;
  int k4 = (idx & 1023) << 2;
  float4 v = reinterpret_cast<const float4*>(a)[idx];
  float xs[4] = {v.x, v.y, v.z, v.w};
  int lw = 0, rw = 0;
#pragma unroll
  for (int t = 0; t < 4; ++t) {
    float x = xs[t];
    int ql = q8(x * 127.0f);
    float inv = 0.104f - 0.899f * fast_tanh((x + 0.056f) * 3.858f);
    int qr = q8(inv * 127.0f);
    lw |= (ql & 255) << (8 * t);
    rw |= (qr & 255) << (8 * t);
  }
  size_t base = (size_t)j * K_DIM + k4;
  *reinterpret_cast<int*>(Ap + base)        = lw;   // a half
  *reinterpret_cast<int*>(Ap + base + K_IN) = rw;   // inv(a) half
}

// ---------------------------------------------------------------------------
// prep_B: th = st(theta*aging); W = |th|/rowsum; per-row q8 with scale
// 127/max|th_ingemm|; B' = [qWp | qWn] i8; corr[i] f32 exact; sc[i] dequant.
// z = acc * sc[i] + corr[i], sc = maxabs/(127*127*rowsum).
// ---------------------------------------------------------------------------
__global__ __launch_bounds__(256) void prep_B(const float* __restrict__ theta,
                                              const float* __restrict__ aging,
                                              int8_t* __restrict__ Bp,
                                              float* __restrict__ corr,
                                              float* __restrict__ sc) {
  __shared__ float th_s[NC];
  __shared__ float red_s[256];
  __shared__ float red_m[256];
  int i = blockIdx.x;
  int tid = threadIdx.x;
  const float* tr = theta + (size_t)i * NC;
  const float* ar = aging + (size_t)i * NC;
  float psum = 0.f, pmax = 0.f;
  for (int k = tid; k < NC; k += 256) {
    float th = tr[k] * ar[k];
    if (fabsf(th) < 0.01f) th = 0.f;
    th_s[k] = th;
    psum += fabsf(th);
    if (k < K_IN) pmax = fmaxf(pmax, fabsf(th));
  }
  red_s[tid] = psum;
  red_m[tid] = pmax;
  __syncthreads();
  for (int s = 128; s > 0; s >>= 1) {
    if (tid < s) {
      red_s[tid] += red_s[tid + s];
      red_m[tid] = fmaxf(red_m[tid], red_m[tid + s]);
    }
    __syncthreads();
  }
  float inv_sum = 1.0f / red_s[0];
  float maxabs  = red_m[0];
  float qs = 127.0f / maxabs;                 // |th| -> quant grid
  int8_t* out = Bp + (size_t)i * K_DIM;
  for (int k0 = tid * 4; k0 < K_IN; k0 += 1024) {
    int pw = 0, nw = 0;
#pragma unroll
    for (int t = 0; t < 4; ++t) {
      float th = th_s[k0 + t];
      int q = q8(fabsf(th) * qs);
      if (th >= 0.f) pw |= (q & 255) << (8 * t);
      else           nw |= (q & 255) << (8 * t);
    }
    *reinterpret_cast<int*>(out + k0)         = pw;   // Wp (pairs with a)
    *reinterpret_cast<int*>(out + K_IN + k0)  = nw;   // Wn (pairs with inv(a))
  }
  if (tid == 0) {
    float th1 = th_s[K_IN];
    float th2 = th_s[K_IN + 1];
    float w1 = fabsf(th1) * inv_sum;
    float w2 = fabsf(th2) * inv_sum;
    float inv1 = 0.104f - 0.899f * fast_tanh((1.0f + 0.056f) * 3.858f);
    float inv0 = 0.104f - 0.899f * fast_tanh((0.0f + 0.056f) * 3.858f);
    float c = (th1 >= 0.f) ? w1 : w1 * inv1;
    c += (th2 >= 0.f) ? 0.0f : w2 * inv0;
    corr[i] = c;
    sc[i] = maxabs * inv_sum * (1.0f / 16129.0f);   // 1/(127*127)
  }
}

// ---------------------------------------------------------------------------
// gemm_fused (i8): 256x256 tile, BKB=128 (K=128 i8), 8 waves (2Mx4N), 4
// phases/K-tile, one barrier per phase (R4-proven schedule, byte-identical
// tile geometry: 256 rows x 128B per matrix per buf). mfma_i32_16x16x64_i8,
// exact i32 accum; dequant z = acc*sc[n] + corr[n] in the epilogue.
// Swizzle: byte col ^= ((row&7)<<4) on both sides (involution pair, rule 21).
// Stage placement: B(W+2) at p2, A(W+2) at p3; vmcnt(8) at p3 (full next
// tile in flight across the boundary), vmcnt(0) for last two windows.
// ---------------------------------------------------------------------------
__global__ __launch_bounds__(512, 2) void gemm_fused(const int8_t* __restrict__ A,
                                                     const int8_t* __restrict__ B,
                                                     const float* __restrict__ corr,
                                                     const float* __restrict__ sc,
                                                     float* __restrict__ C) {
  extern __shared__ char lds[];   // 131072 B
  const int tid  = threadIdx.x;
  const int lane = tid & 63;
  const int wid  = tid >> 6;     // 0..7
  const int wr   = wid >> 2;     // 0..1  -> M offset wr*128
  const int wc   = wid & 3;      // 0..3  -> N offset wc*64
  const int fr   = lane & 15;

  // T1: XCD-aware swizzle; nwg = 512, divisible by 8 -> bijective
  const int bid = (int)blockIdx.x;
  const int sw  = (bid & 7) * 64 + (bid >> 3);
  const int bm0 = (sw >> 4) * BM;     // 32 M-blocks
  const int bn0 = (sw & 15) * BN;     // 16 N-blocks

  // staging: linear LDS dest (glds), per-lane GLOBAL source col pre-swizzled
  const int colsw = ((tid & 7) * 16) ^ (((tid >> 3) & 7) << 4);   // bytes
  const int8_t* gA = A + (size_t)(bm0 + (tid >> 3)) * K_DIM + colsw;
  const int8_t* gB = B + (size_t)(bn0 + (tid >> 3)) * K_DIM + colsw;
  const int dst_t = tid * 16;

  // read-side swizzled fragment byte offsets (within a 128B row)
  const int flip = (fr & 7) << 4;
  const int cs0  = ((lane >> 4) * 16) ^ flip;          // kk=0
  const int cs1  = (64 + (lane >> 4) * 16) ^ flip;     // kk=1
  const int aRow = (wr * 128 + fr) * BKB;              // byte offset of frag row
  const int bRow = (wc * 64 + fr) * BKB;

  i32x4 acc[8][4] = {};

#define STAGE(ISA, H, T) do {                                                        \
    const int8_t* _g = (ISA) ? gA : gB;                                              \
    const size_t _go = (size_t)((H) * 128) * K_DIM + (size_t)(T) * BKB;              \
    char* _l = lds + (((T) & 1) * 65536) + ((ISA) ? 0 : 32768) + (H) * 16384 + dst_t; \
    __builtin_amdgcn_global_load_lds(                                                \
        (const __attribute__((address_space(1))) unsigned int*)(_g + _go),           \
        (__attribute__((address_space(3))) unsigned int*)_l, 16, 0, 0);              \
    __builtin_amdgcn_global_load_lds(                                                \
        (const __attribute__((address_space(1))) unsigned int*)(_g + _go + (size_t)64 * K_DIM), \
        (__attribute__((address_space(3))) unsigned int*)(_l + 8192), 16, 0, 0);     \
  } while (0)

#define MFMA(a, b, c) __builtin_amdgcn_mfma_i32_16x16x64_i8((a), (b), (c), 0, 0, 0)

  // ---- prologue: tile0 + tile1 fully staged (16 loads); wait tile0 (8 left)
  STAGE(0, 0, 0); STAGE(0, 1, 0); STAGE(1, 0, 0); STAGE(1, 1, 0);
  STAGE(0, 0, 1); STAGE(0, 1, 1); STAGE(1, 0, 1); STAGE(1, 1, 1);
  asm volatile("s_waitcnt vmcnt(8)" ::: "memory");
  __builtin_amdgcn_s_barrier();

#pragma unroll 2
  for (int W = 0; W < NT; ++W) {
    const char* pa = lds + (W & 1) * 65536 + aRow;
    const char* pb = lds + (W & 1) * 65536 + 32768 + bRow;
    i32x4 af[4][2], bf[4][2];

    // ===== phase 0: read A m0-3 (8) + B n0-1 (4) | barrier | MFMA q00
#pragma unroll
    for (int m = 0; m < 4; ++m) {
      af[m][0] = *(const i32x4*)(pa + m * 16 * BKB + cs0);
      af[m][1] = *(const i32x4*)(pa + m * 16 * BKB + cs1);
    }
#pragma unroll
    for (int n = 0; n < 2; ++n) {
      bf[n][0] = *(const i32x4*)(pb + n * 16 * BKB + cs0);
      bf[n][1] = *(const i32x4*)(pb + n * 16 * BKB + cs1);
    }
    __builtin_amdgcn_s_barrier();
    asm volatile("s_waitcnt lgkmcnt(0)" ::: "memory");
    __builtin_amdgcn_sched_barrier(0);
    __builtin_amdgcn_s_setprio(1);
#pragma unroll
    for (int m = 0; m < 4; ++m)
#pragma unroll
      for (int n = 0; n < 2; ++n) {
        acc[m][n] = MFMA(af[m][0], bf[n][0], acc[m][n]);
        acc[m][n] = MFMA(af[m][1], bf[n][1], acc[m][n]);
      }
    __builtin_amdgcn_s_setprio(0);

    // ===== phase 1: read B n2-3 (4) | barrier | MFMA q01
#pragma unroll
    for (int n = 2; n < 4; ++n) {
      bf[n][0] = *(const i32x4*)(pb + n * 16 * BKB + cs0);
      bf[n][1] = *(const i32x4*)(pb + n * 16 * BKB + cs1);
    }
    __builtin_amdgcn_s_barrier();
    asm volatile("s_waitcnt lgkmcnt(0)" ::: "memory");
    __builtin_amdgcn_sched_barrier(0);
    __builtin_amdgcn_s_setprio(1);
#pragma unroll
    for (int m = 0; m < 4; ++m)
#pragma unroll
      for (int n = 2; n < 4; ++n) {
        acc[m][n] = MFMA(af[m][0], bf[n][0], acc[m][n]);
        acc[m][n] = MFMA(af[m][1], bf[n][1], acc[m][n]);
      }
    __builtin_amdgcn_s_setprio(0);

    // ===== phase 2: read A m4-7 (8); stage B(W+2) | barrier | MFMA q10
#pragma unroll
    for (int m = 0; m < 4; ++m) {
      af[m][0] = *(const i32x4*)(pa + (m + 4) * 16 * BKB + cs0);
      af[m][1] = *(const i32x4*)(pa + (m + 4) * 16 * BKB + cs1);
    }
    if (W + 2 < NT) { STAGE(0, 0, W + 2); STAGE(0, 1, W + 2); }
    __builtin_amdgcn_s_barrier();
    asm volatile("s_waitcnt lgkmcnt(0)" ::: "memory");
    __builtin_amdgcn_sched_barrier(0);
    __builtin_amdgcn_s_setprio(1);
#pragma unroll
    for (int m = 0; m < 4; ++m)
#pragma unroll
      for (int n = 0; n < 2; ++n) {
        acc[m + 4][n] = MFMA(af[m][0], bf[n][0], acc[m + 4][n]);
        acc[m + 4][n] = MFMA(af[m][1], bf[n][1], acc[m + 4][n]);
      }
    __builtin_amdgcn_s_setprio(0);

    // ===== phase 3: stage A(W+2); counted vmcnt | barrier | MFMA q11
    if (W + 2 < NT) { STAGE(1, 0, W + 2); STAGE(1, 1, W + 2); }
    if (W < NT - 2) { asm volatile("s_waitcnt vmcnt(8)" ::: "memory"); }
    else            { asm volatile("s_waitcnt vmcnt(0)" ::: "memory"); }
    __builtin_amdgcn_s_barrier();
    __builtin_amdgcn_sched_barrier(0);
    __builtin_amdgcn_s_setprio(1);
#pragma unroll
    for (int m = 0; m < 4; ++m)
#pragma unroll
      for (int n = 2; n < 4; ++n) {
        acc[m + 4][n] = MFMA(af[m][0], bf[n][0], acc[m + 4][n]);
        acc[m + 4][n] = MFMA(af[m][1], bf[n][1], acc[m + 4][n]);
      }
    __builtin_amdgcn_s_setprio(0);
  }

  // ---- epilogue: z = acc*sc[n] + corr[n]; activation; store
  const int rb = (lane >> 4) * 4;
#pragma unroll
  for (int n = 0; n < 4; ++n) {
    const int col = bn0 + wc * 64 + n * 16 + fr;
    const float cr = corr[col];
    const float s  = sc[col];
#pragma unroll
    for (int mi = 0; mi < 8; ++mi) {
      const int row0 = bm0 + wr * 128 + mi * 16 + rb;
#pragma unroll
      for (int j = 0; j < 4; ++j) {
        float z = (float)acc[mi][n][j] * s + cr;
        float e = __expf((z - 0.183f) * 48.2f);
        C[(size_t)(row0 + j) * N_DIM + col] = 1.096f - 1.924f * __builtin_amdgcn_rcpf(1.0f + e);
      }
    }
  }
#undef STAGE
#undef MFMA
}

// ---------------------------------------------------------------------------
extern "C" void kernel_launch(void* const* d_in, const int* in_sizes, int n_in,
                              void* d_out, int out_size, void* d_ws, size_t ws_size,
                              hipStream_t stream) {
  (void)in_sizes; (void)n_in; (void)out_size; (void)ws_size;
  const float* a_prev = (const float*)d_in[0];
  const float* theta  = (const float*)d_in[1];
  const float* aging  = (const float*)d_in[2];
  float* out = (float*)d_out;

  char* ws = (char*)d_ws;
  int8_t* Ap = (int8_t*)ws;                                        // 67.1 MB
  int8_t* Bp = (int8_t*)(ws + (size_t)M_DIM * K_DIM);              // 33.6 MB
  float* corr = (float*)(ws + (size_t)M_DIM * K_DIM + (size_t)N_DIM * K_DIM);
  float* sc   = corr + N_DIM;

  prep_A<<<(M_DIM * K_IN / 4) / 256, 256, 0, stream>>>(a_prev, Ap);
  prep_B<<<N_DIM, 256, 0, stream>>>(theta, aging, Bp, corr, sc);

  (void)hipFuncSetAttribute((const void*)gemm_fused,
                            hipFuncAttributeMaxDynamicSharedMemorySize, 131072);
  gemm_fused<<<dim3((M_DIM / BM) * (N_DIM / BN)), dim3(512), 131072, stream>>>(Ap, Bp, corr, sc, out);
}